// Round 3
// baseline (2677.324 us; speedup 1.0000x reference)
//
#include <hip/hip_runtime.h>
#include <stdint.h>

#define BB 8
#define NN 4096
#define CC 64
#define MM 1024
#define EE (BB*MM)   // 8192 centroids
#define KK 64        // max neighbors
#define F3 256       // output channels
#define SM 104       // msg LDS stride (elements), 16B-aligned rows (208 B)
#define SH 136       // h1/h2 LDS stride (elements), 16B-aligned rows (272 B)
#define CAP 768      // candidate buffer

typedef __bf16 bf16x8 __attribute__((ext_vector_type(8)));
typedef float floatx4 __attribute__((ext_vector_type(4)));

// ---------------- FPS: one block per graph, exact np-f32 arithmetic ----------------
__global__ __launch_bounds__(1024) void fps_kernel(const float* __restrict__ pos,
                                                   int* __restrict__ fpsIdx,
                                                   float* __restrict__ ctr) {
  const int g = blockIdx.x;
  const int t = threadIdx.x;
  float px[4], py[4], pz[4], mind[4];
#pragma unroll
  for (int j = 0; j < 4; ++j) {
    const int p = t + (j << 10);
    const long base = ((long)g * NN + p) * 3;
    px[j] = pos[base + 0];
    py[j] = pos[base + 1];
    pz[j] = pos[base + 2];
    mind[j] = 1e10f;
  }
  __shared__ float sC[3];
  __shared__ float sWv[16];
  __shared__ int   sWi[16];
  __shared__ int   sWin;
  if (t == 0) {
    fpsIdx[g * MM] = 0;
    ctr[((long)g * MM) * 3 + 0] = px[0];
    ctr[((long)g * MM) * 3 + 1] = py[0];
    ctr[((long)g * MM) * 3 + 2] = pz[0];
    sC[0] = px[0]; sC[1] = py[0]; sC[2] = pz[0];
  }
  __syncthreads();
  const int lane = t & 63;
  const int wv = t >> 6;
  for (int s = 1; s < MM; ++s) {
    const float cx = sC[0], cy = sC[1], cz = sC[2];
    float bv = -1.0f; int bi = 0;
#pragma unroll
    for (int j = 0; j < 4; ++j) {
      const float dx = __fsub_rn(px[j], cx);
      const float dy = __fsub_rn(py[j], cy);
      const float dz = __fsub_rn(pz[j], cz);
      const float d2 = __fadd_rn(__fadd_rn(__fmul_rn(dx, dx), __fmul_rn(dy, dy)), __fmul_rn(dz, dz));
      mind[j] = fminf(mind[j], d2);
      if (mind[j] > bv) { bv = mind[j]; bi = t + (j << 10); }
    }
#pragma unroll
    for (int off = 32; off >= 1; off >>= 1) {
      const float ov = __shfl_xor(bv, off);
      const int   oi = __shfl_xor(bi, off);
      if (ov > bv || (ov == bv && oi < bi)) { bv = ov; bi = oi; }
    }
    if (lane == 0) { sWv[wv] = bv; sWi[wv] = bi; }
    __syncthreads();
    if (t < 64) {
      float v = (t < 16) ? sWv[t] : -2.0f;
      int  i2 = (t < 16) ? sWi[t] : 0x7fffffff;
#pragma unroll
      for (int off = 8; off >= 1; off >>= 1) {
        const float ov = __shfl_xor(v, off);
        const int   oi = __shfl_xor(i2, off);
        if (ov > v || (ov == v && oi < i2)) { v = ov; i2 = oi; }
      }
      if (t == 0) sWin = i2;
    }
    __syncthreads();
    const int win = sWin;
    if (t == (win & 1023)) {
      const int j = win >> 10;
      sC[0] = px[j]; sC[1] = py[j]; sC[2] = pz[j];
      fpsIdx[g * MM + s] = win;
      ctr[((long)g * MM + s) * 3 + 0] = px[j];
      ctr[((long)g * MM + s) * 3 + 1] = py[j];
      ctr[((long)g * MM + s) * 3 + 2] = pz[j];
    }
    __syncthreads();
  }
}

// ---------------- x: f32 -> bf16 (one-time, 2M elements) ----------------
__global__ void xcvt_kernel(const float* __restrict__ x, __bf16* __restrict__ xb) {
  const int t = blockIdx.x * 256 + threadIdx.x;   // 524288 threads, 4 elems each
  const float4 v = ((const float4*)x)[t];
  __bf16 o[4] = {(__bf16)v.x, (__bf16)v.y, (__bf16)v.z, (__bf16)v.w};
  *(uint2*)(xb + (long)t * 4) = *(uint2*)o;
}

// -------- Weight transpose (f32 -> bf16): Wt[n][k], k-contiguous; W1 K 67->96 --------
__global__ void wprep_kernel(const float* __restrict__ W1, const float* __restrict__ W2,
                             const float* __restrict__ W3,
                             __bf16* __restrict__ W1t, __bf16* __restrict__ W2t,
                             __bf16* __restrict__ W3t) {
  const int t = blockIdx.x * 256 + threadIdx.x;
  if (t < 128 * 96) {
    const int n = t / 96, k = t % 96;
    W1t[t] = (k < 67) ? (__bf16)W1[k * 128 + n] : (__bf16)0.0f;
  } else if (t < 128 * 96 + 128 * 128) {
    const int i = t - 128 * 96;
    const int n = i / 128, k = i % 128;
    W2t[i] = (__bf16)W2[k * 128 + n];
  } else if (t < 128 * 96 + 128 * 128 + 256 * 128) {
    const int i = t - (128 * 96 + 128 * 128);
    const int n = i / 128, k = i % 128;
    W3t[i] = (__bf16)W3[k * 256 + n];
  }
}

// ---------------- Tail outputs: pos/batch/seed (all f32, exact) ----------------
__global__ void tail_kernel(const float* __restrict__ pos, const int* __restrict__ fpsIdx,
                            float* __restrict__ outP, float* __restrict__ outB,
                            float* __restrict__ outS) {
  const int e = blockIdx.x * 256 + threadIdx.x;
  if (e >= EE) return;
  const int g = e >> 10;
  const int gi = g * NN + fpsIdx[e];
  outP[(long)e * 3 + 0] = pos[(long)gi * 3 + 0];
  outP[(long)e * 3 + 1] = pos[(long)gi * 3 + 1];
  outP[(long)e * 3 + 2] = pos[(long)gi * 3 + 2];
  outB[e] = (float)g;
  outS[e] = (float)gi;
}

// ---- Fused radius-search + top-K + gather + 3-layer MLP (bf16 MFMA) + masked max ----
// One block (512 thr = 8 waves) per centroid.
__global__ __launch_bounds__(512) void mlp_kernel(const __bf16* __restrict__ xb,
    const float* __restrict__ pos, const float* __restrict__ ctr,
    const __bf16* __restrict__ W1t, const __bf16* __restrict__ W2t,
    const __bf16* __restrict__ W3t,
    const float* __restrict__ b1, const float* __restrict__ b2,
    const float* __restrict__ b3,
    float* __restrict__ outX) {
  __shared__ float sD[CAP];
  __shared__ int   sI[CAP];
  __shared__ int   sSel[KK];
  __shared__ int   sCnt;
  __shared__ __align__(16) __bf16 sMsg[64 * SM];
  __shared__ __align__(16) __bf16 sH1[64 * SH];
  __shared__ __align__(16) __bf16 sH2[64 * SH];

  const int e = blockIdx.x;
  const int t = threadIdx.x;
  const int b = e >> 10;
  const int lane = t & 63, wv = t >> 6;

  if (t == 0) sCnt = 0;
  const float cx = ctr[(long)e * 3 + 0];
  const float cy = ctr[(long)e * 3 + 1];
  const float cz = ctr[(long)e * 3 + 2];
  const float R2 = (float)(0.2 * 0.2);
  const long pbase = (long)b * NN * 3;
  __syncthreads();

  // Phase A: scan 4096 points; compact in-radius candidates to LDS (order-free).
#pragma unroll
  for (int q = 0; q < NN / 512; ++q) {
    const int p = t + q * 512;
    const float dx = __fsub_rn(cx, pos[pbase + (long)p * 3 + 0]);
    const float dy = __fsub_rn(cy, pos[pbase + (long)p * 3 + 1]);
    const float dz = __fsub_rn(cz, pos[pbase + (long)p * 3 + 2]);
    const float d2 = __fadd_rn(__fadd_rn(__fmul_rn(dx, dx), __fmul_rn(dy, dy)), __fmul_rn(dz, dz));
    if (d2 < R2) {
      const int slot = atomicAdd(&sCnt, 1);
      if (slot < CAP) { sD[slot] = d2; sI[slot] = p; }
    }
  }
  __syncthreads();
  int cnt = sCnt; cnt = cnt > CAP ? CAP : cnt;

  // Phase B: if over K, select the K smallest by (d2, idx); else take all.
  if (cnt > KK) {
    if (wv == 0) {
      float ld[CAP / 64]; int li[CAP / 64];
#pragma unroll
      for (int q = 0; q < CAP / 64; ++q) {
        const int pp = lane + q * 64;
        if (pp < cnt) { ld[q] = sD[pp]; li[q] = sI[pp]; }
        else          { ld[q] = 3.0e38f; li[q] = 0x7fffffff; }
      }
      for (int round = 0; round < KK; ++round) {
        float bv = ld[0]; int bi = li[0];
#pragma unroll
        for (int q = 1; q < CAP / 64; ++q)
          if (ld[q] < bv || (ld[q] == bv && li[q] < bi)) { bv = ld[q]; bi = li[q]; }
#pragma unroll
        for (int off = 32; off >= 1; off >>= 1) {
          const float ov = __shfl_xor(bv, off);
          const int   oi = __shfl_xor(bi, off);
          if (ov < bv || (ov == bv && oi < bi)) { bv = ov; bi = oi; }
        }
        if (lane == 0) sSel[round] = bi;
#pragma unroll
        for (int q = 0; q < CAP / 64; ++q)
          if (li[q] == bi) ld[q] = 3.0e38f;
      }
    }
    cnt = KK;
  } else {
    if (wv == 0 && lane < cnt) sSel[lane] = sI[lane];
  }
  __syncthreads();

  // Phase C: stage msg tile [64 x (64 feat | 3 dpos | zero-pad)] into LDS as bf16.
  {
    const int r = t >> 3, p = t & 7;
    uint4 val = make_uint4(0u, 0u, 0u, 0u);
    if (r < cnt) {
      const int j = b * NN + sSel[r];
      val = *(const uint4*)(xb + (long)j * CC + p * 8);
    }
    *(uint4*)&sMsg[r * SM + p * 8] = val;
  }
  if (t < 64) {
    const int r = t;
    __bf16 d0 = (__bf16)0.0f, d1 = (__bf16)0.0f, d2v = (__bf16)0.0f;
    if (r < cnt) {
      const long j = pbase + (long)sSel[r] * 3;
      d0  = (__bf16)__fsub_rn(pos[j + 0], cx);
      d1  = (__bf16)__fsub_rn(pos[j + 1], cy);
      d2v = (__bf16)__fsub_rn(pos[j + 2], cz);
    }
    sMsg[r * SM + 64] = d0;
    sMsg[r * SM + 65] = d1;
    sMsg[r * SM + 66] = d2v;
    for (int c = 67; c < SM; ++c) sMsg[r * SM + c] = (__bf16)0.0f;
  }
  __syncthreads();

  const int l15 = lane & 15, quad = lane >> 4;
  // ---- layer 1: [64 x 96] @ [96 x 128]; wave wv owns n-tile wv ----
  {
    floatx4 acc[4] = {};
    const __bf16* wrow = W1t + (wv * 16 + l15) * 96;
#pragma unroll
    for (int ks = 0; ks < 3; ++ks) {
      const bf16x8 bfrag = *(const bf16x8*)(wrow + ks * 32 + quad * 8);
#pragma unroll
      for (int mt = 0; mt < 4; ++mt) {
        const bf16x8 afrag = *(const bf16x8*)&sMsg[(mt * 16 + l15) * SM + ks * 32 + quad * 8];
        acc[mt] = __builtin_amdgcn_mfma_f32_16x16x32_bf16(afrag, bfrag, acc[mt], 0, 0, 0);
      }
    }
    const int col = wv * 16 + l15;
    const float bias = b1[col];
#pragma unroll
    for (int mt = 0; mt < 4; ++mt)
#pragma unroll
      for (int rg = 0; rg < 4; ++rg) {
        const int row = mt * 16 + quad * 4 + rg;
        float v = acc[mt][rg] + bias;
        v = v > 0.0f ? v : 0.0f;
        sH1[row * SH + col] = (__bf16)v;
      }
  }
  __syncthreads();
  // ---- layer 2: [64 x 128] @ [128 x 128] ----
  {
    floatx4 acc[4] = {};
    const __bf16* wrow = W2t + (wv * 16 + l15) * 128;
#pragma unroll
    for (int ks = 0; ks < 4; ++ks) {
      const bf16x8 bfrag = *(const bf16x8*)(wrow + ks * 32 + quad * 8);
#pragma unroll
      for (int mt = 0; mt < 4; ++mt) {
        const bf16x8 afrag = *(const bf16x8*)&sH1[(mt * 16 + l15) * SH + ks * 32 + quad * 8];
        acc[mt] = __builtin_amdgcn_mfma_f32_16x16x32_bf16(afrag, bfrag, acc[mt], 0, 0, 0);
      }
    }
    const int col = wv * 16 + l15;
    const float bias = b2[col];
#pragma unroll
    for (int mt = 0; mt < 4; ++mt)
#pragma unroll
      for (int rg = 0; rg < 4; ++rg) {
        const int row = mt * 16 + quad * 4 + rg;
        float v = acc[mt][rg] + bias;
        v = v > 0.0f ? v : 0.0f;
        sH2[row * SH + col] = (__bf16)v;
      }
  }
  __syncthreads();
  // ---- layer 3: [64 x 128] @ [128 x 256]; wave owns 2 n-tiles; fused masked max ----
  {
    floatx4 acc[2][4] = {};
#pragma unroll
    for (int ks = 0; ks < 4; ++ks) {
      bf16x8 afrag[4];
#pragma unroll
      for (int mt = 0; mt < 4; ++mt)
        afrag[mt] = *(const bf16x8*)&sH2[(mt * 16 + l15) * SH + ks * 32 + quad * 8];
#pragma unroll
      for (int i = 0; i < 2; ++i) {
        const bf16x8 bfrag = *(const bf16x8*)(W3t + ((wv * 2 + i) * 16 + l15) * 128 + ks * 32 + quad * 8);
#pragma unroll
        for (int mt = 0; mt < 4; ++mt)
          acc[i][mt] = __builtin_amdgcn_mfma_f32_16x16x32_bf16(afrag[mt], bfrag, acc[i][mt], 0, 0, 0);
      }
    }
#pragma unroll
    for (int i = 0; i < 2; ++i) {
      const int col = (wv * 2 + i) * 16 + l15;
      const float bias = b3[col];
      float mx = 0.0f;  // centroid itself always in-radius => cnt>=1; ReLU >= 0
#pragma unroll
      for (int mt = 0; mt < 4; ++mt)
#pragma unroll
        for (int rg = 0; rg < 4; ++rg) {
          const int row = mt * 16 + quad * 4 + rg;
          float v = acc[i][mt][rg] + bias;
          v = v > 0.0f ? v : 0.0f;
          if (row < cnt) mx = fmaxf(mx, v);
        }
      mx = fmaxf(mx, __shfl_xor(mx, 16));
      mx = fmaxf(mx, __shfl_xor(mx, 32));
      if (quad == 0) outX[(long)e * F3 + col] = mx;
    }
  }
}

extern "C" void kernel_launch(void* const* d_in, const int* in_sizes, int n_in,
                              void* d_out, int out_size, void* d_ws, size_t ws_size,
                              hipStream_t stream) {
  const float* x   = (const float*)d_in[0];
  const float* pos = (const float*)d_in[1];
  const float* W1  = (const float*)d_in[4];
  const float* b1  = (const float*)d_in[5];
  const float* W2  = (const float*)d_in[6];
  const float* b2  = (const float*)d_in[7];
  const float* W3  = (const float*)d_in[8];
  const float* b3  = (const float*)d_in[9];

  // Workspace layout (~4.25 MB)
  char* ws = (char*)d_ws;
  int*    fpsIdx = (int*)(ws);                 // 8192*4        = 32768
  float*  ctr    = (float*)(ws + 32768);       // 8192*3*4      = 98304   (ends 131072)
  __bf16* W1t    = (__bf16*)(ws + 131072);     // 128*96*2      = 24576   (ends 155648)
  __bf16* W2t    = (__bf16*)(ws + 155648);     // 128*128*2     = 32768   (ends 188416)
  __bf16* W3t    = (__bf16*)(ws + 188416);     // 256*128*2     = 65536   (ends 253952)
  __bf16* xb     = (__bf16*)(ws + 253952);     // 32768*64*2    = 4194304 (ends 4448256)

  float* outX = (float*)d_out;                 // [8192,256]
  float* outP = outX + (long)EE * F3;          // [8192,3]
  float* outB = outP + (long)EE * 3;           // [8192]
  float* outS = outB + EE;                     // [8192]

  fps_kernel<<<BB, 1024, 0, stream>>>(pos, fpsIdx, ctr);
  xcvt_kernel<<<2048, 256, 0, stream>>>(x, xb);
  wprep_kernel<<<240, 256, 0, stream>>>(W1, W2, W3, W1t, W2t, W3t);
  tail_kernel<<<EE / 256, 256, 0, stream>>>(pos, fpsIdx, outP, outB, outS);
  mlp_kernel<<<EE, 512, 0, stream>>>(xb, pos, ctr, W1t, W2t, W3t, b1, b2, b3, outX);
}

// Round 4
// 1966.926 us; speedup vs baseline: 1.3612x; 1.3612x over previous
//
#include <hip/hip_runtime.h>
#include <stdint.h>

#define BB 8
#define NN 4096
#define CC 64
#define MM 1024
#define EE (BB*MM)   // 8192 centroids
#define KK 64        // max neighbors
#define F3 256       // output channels
#define SM 104       // msg LDS stride (elements), 16B-aligned rows (208 B)
#define SH 136       // h LDS stride (elements), 16B-aligned rows (272 B)
#define CAP 768      // candidate buffer

typedef __bf16 bf16x8 __attribute__((ext_vector_type(8)));
typedef float floatx4 __attribute__((ext_vector_type(4)));

// ---------------- FPS: one block/graph, ONE barrier per step ----------------
// Positions live in LDS (48 KB) so the winner's xyz is a broadcast read, and
// the (value,index) argmax is a packed-u64 integer max (tie -> smaller index,
// matching np.argmax first-max). All arithmetic _rn, np evaluation order.
__global__ __launch_bounds__(1024) void fps_kernel(const float* __restrict__ pos,
                                                   int* __restrict__ fpsIdx,
                                                   float* __restrict__ ctr) {
  const int g = blockIdx.x, t = threadIdx.x;
  const int lane = t & 63, wv = t >> 6;
  __shared__ float sPx[NN], sPy[NN], sPz[NN];
  __shared__ unsigned long long sRed[2][16];
  float px[4], py[4], pz[4], mind[4];
  unsigned int nidx[4];
#pragma unroll
  for (int j = 0; j < 4; ++j) {
    const int p = t + (j << 10);
    const long base = ((long)g * NN + p) * 3;
    px[j] = pos[base + 0];
    py[j] = pos[base + 1];
    pz[j] = pos[base + 2];
    mind[j] = 1e10f;
    nidx[j] = ~(unsigned int)p;
    sPx[p] = px[j]; sPy[p] = py[j]; sPz[p] = pz[j];
  }
  if (t == 0) {
    fpsIdx[g * MM] = 0;
    ctr[((long)g * MM) * 3 + 0] = px[0];
    ctr[((long)g * MM) * 3 + 1] = py[0];
    ctr[((long)g * MM) * 3 + 2] = pz[0];
  }
  __syncthreads();
  float wx = sPx[0], wy = sPy[0], wz = sPz[0];
  for (int s = 1; s < MM; ++s) {
    unsigned long long best = 0ull;
#pragma unroll
    for (int j = 0; j < 4; ++j) {
      const float dx = __fsub_rn(px[j], wx);
      const float dy = __fsub_rn(py[j], wy);
      const float dz = __fsub_rn(pz[j], wz);
      const float d2 = __fadd_rn(__fadd_rn(__fmul_rn(dx, dx), __fmul_rn(dy, dy)), __fmul_rn(dz, dz));
      mind[j] = fminf(mind[j], d2);
      const unsigned long long pk =
          ((unsigned long long)__float_as_uint(mind[j]) << 32) | (unsigned long long)nidx[j];
      best = pk > best ? pk : best;
    }
#pragma unroll
    for (int off = 32; off >= 1; off >>= 1) {
      const unsigned long long o = __shfl_xor(best, off);
      best = o > best ? o : best;
    }
    if (lane == 0) sRed[s & 1][wv] = best;
    __syncthreads();
    unsigned long long v = sRed[s & 1][lane & 15];
#pragma unroll
    for (int off = 8; off >= 1; off >>= 1) {
      const unsigned long long o = __shfl_xor(v, off);
      v = o > v ? o : v;
    }
    const int widx = (int)(~(unsigned int)v);
    wx = sPx[widx]; wy = sPy[widx]; wz = sPz[widx];
    if (t == 0) {
      fpsIdx[g * MM + s] = widx;
      ctr[((long)g * MM + s) * 3 + 0] = wx;
      ctr[((long)g * MM + s) * 3 + 1] = wy;
      ctr[((long)g * MM + s) * 3 + 2] = wz;
    }
  }
}

// ---------------- x: f32 -> bf16 (one-time, 2M elements) ----------------
__global__ void xcvt_kernel(const float* __restrict__ x, __bf16* __restrict__ xb) {
  const int t = blockIdx.x * 256 + threadIdx.x;
  const float4 v = ((const float4*)x)[t];
  __bf16 o[4] = {(__bf16)v.x, (__bf16)v.y, (__bf16)v.z, (__bf16)v.w};
  *(uint2*)(xb + (long)t * 4) = *(uint2*)o;
}

// -------- Weight transpose (f32 -> bf16): Wt[n][k], k-contiguous; W1 K 67->96 --------
__global__ void wprep_kernel(const float* __restrict__ W1, const float* __restrict__ W2,
                             const float* __restrict__ W3,
                             __bf16* __restrict__ W1t, __bf16* __restrict__ W2t,
                             __bf16* __restrict__ W3t) {
  const int t = blockIdx.x * 256 + threadIdx.x;
  if (t < 128 * 96) {
    const int n = t / 96, k = t % 96;
    W1t[t] = (k < 67) ? (__bf16)W1[k * 128 + n] : (__bf16)0.0f;
  } else if (t < 128 * 96 + 128 * 128) {
    const int i = t - 128 * 96;
    const int n = i / 128, k = i % 128;
    W2t[i] = (__bf16)W2[k * 128 + n];
  } else if (t < 128 * 96 + 128 * 128 + 256 * 128) {
    const int i = t - (128 * 96 + 128 * 128);
    const int n = i / 128, k = i % 128;
    W3t[i] = (__bf16)W3[k * 256 + n];
  }
}

// ---------------- Tail outputs: pos/batch/seed (all f32, exact) ----------------
__global__ void tail_kernel(const float* __restrict__ pos, const int* __restrict__ fpsIdx,
                            float* __restrict__ outP, float* __restrict__ outB,
                            float* __restrict__ outS) {
  const int e = blockIdx.x * 256 + threadIdx.x;
  if (e >= EE) return;
  const int g = e >> 10;
  const int gi = g * NN + fpsIdx[e];
  outP[(long)e * 3 + 0] = pos[(long)gi * 3 + 0];
  outP[(long)e * 3 + 1] = pos[(long)gi * 3 + 1];
  outP[(long)e * 3 + 2] = pos[(long)gi * 3 + 2];
  outB[e] = (float)g;
  outS[e] = (float)gi;
}

// ---- Fused radius-search + top-K + gather + 3-layer MLP (bf16 MFMA) + masked max ----
// One block (512 thr = 8 waves) per centroid. LDS budget ~31 KB:
//  - sD/sI candidate arrays overlay sMsg (unused until Phase C)
//  - layer 2 writes IN PLACE into sH (read-all -> barrier -> write-back)
__global__ __launch_bounds__(512) void mlp_kernel(const __bf16* __restrict__ xb,
    const float* __restrict__ pos, const float* __restrict__ ctr,
    const __bf16* __restrict__ W1t, const __bf16* __restrict__ W2t,
    const __bf16* __restrict__ W3t,
    const float* __restrict__ b1, const float* __restrict__ b2,
    const float* __restrict__ b3,
    float* __restrict__ outX) {
  __shared__ __align__(16) __bf16 sMsg[64 * SM];   // 13312 B; overlays sD+sI (6144 B)
  __shared__ __align__(16) __bf16 sH[64 * SH];     // 17408 B
  __shared__ int sSel[KK];
  __shared__ int sCnt;
  float* sD = (float*)sMsg;          // [CAP]
  int*   sI = ((int*)sMsg) + CAP;    // [CAP]

  const int e = blockIdx.x;
  const int t = threadIdx.x;
  const int b = e >> 10;
  const int lane = t & 63, wv = t >> 6;

  if (t == 0) sCnt = 0;
  const float cx = ctr[(long)e * 3 + 0];
  const float cy = ctr[(long)e * 3 + 1];
  const float cz = ctr[(long)e * 3 + 2];
  const float R2 = (float)(0.2 * 0.2);
  const long pbase = (long)b * NN * 3;
  __syncthreads();

  // Phase A: scan 4096 points; compact in-radius candidates to LDS (order-free).
#pragma unroll
  for (int q = 0; q < NN / 512; ++q) {
    const int p = t + q * 512;
    const float dx = __fsub_rn(cx, pos[pbase + (long)p * 3 + 0]);
    const float dy = __fsub_rn(cy, pos[pbase + (long)p * 3 + 1]);
    const float dz = __fsub_rn(cz, pos[pbase + (long)p * 3 + 2]);
    const float d2 = __fadd_rn(__fadd_rn(__fmul_rn(dx, dx), __fmul_rn(dy, dy)), __fmul_rn(dz, dz));
    if (d2 < R2) {
      const int slot = atomicAdd(&sCnt, 1);
      if (slot < CAP) { sD[slot] = d2; sI[slot] = p; }
    }
  }
  __syncthreads();
  int cnt = sCnt; cnt = cnt > CAP ? CAP : cnt;

  // Phase B: if over K, select the K smallest by (d2, idx); else take all.
  if (cnt > KK) {
    if (wv == 0) {
      float ld[CAP / 64]; int li[CAP / 64];
#pragma unroll
      for (int q = 0; q < CAP / 64; ++q) {
        const int pp = lane + q * 64;
        if (pp < cnt) { ld[q] = sD[pp]; li[q] = sI[pp]; }
        else          { ld[q] = 3.0e38f; li[q] = 0x7fffffff; }
      }
      for (int round = 0; round < KK; ++round) {
        float bv = ld[0]; int bi = li[0];
#pragma unroll
        for (int q = 1; q < CAP / 64; ++q)
          if (ld[q] < bv || (ld[q] == bv && li[q] < bi)) { bv = ld[q]; bi = li[q]; }
#pragma unroll
        for (int off = 32; off >= 1; off >>= 1) {
          const float ov = __shfl_xor(bv, off);
          const int   oi = __shfl_xor(bi, off);
          if (ov < bv || (ov == bv && oi < bi)) { bv = ov; bi = oi; }
        }
        if (lane == 0) sSel[round] = bi;
#pragma unroll
        for (int q = 0; q < CAP / 64; ++q)
          if (li[q] == bi) ld[q] = 3.0e38f;
      }
    }
    cnt = KK;
  } else {
    if (wv == 0 && lane < cnt) sSel[lane] = sI[lane];
  }
  __syncthreads();   // sD/sI dead from here; sMsg may be written

  // Phase C: stage msg tile [64 x (64 feat | 3 dpos | zero-pad)] into LDS as bf16.
  {
    const int r = t >> 3, p = t & 7;
    uint4 val = make_uint4(0u, 0u, 0u, 0u);
    int j = 0;
    if (r < cnt) j = b * NN + sSel[r];
    if (r < cnt) val = *(const uint4*)(xb + (long)j * CC + p * 8);
    __syncthreads();  // ensure all Phase-B reads of sD/sI done before overwrite
    *(uint4*)&sMsg[r * SM + p * 8] = val;
  }
  if (t < 64) {
    const int r = t;
    __bf16 d0 = (__bf16)0.0f, d1 = (__bf16)0.0f, d2v = (__bf16)0.0f;
    if (r < cnt) {
      const long j = pbase + (long)sSel[r] * 3;
      d0  = (__bf16)__fsub_rn(pos[j + 0], cx);
      d1  = (__bf16)__fsub_rn(pos[j + 1], cy);
      d2v = (__bf16)__fsub_rn(pos[j + 2], cz);
    }
    sMsg[r * SM + 64] = d0;
    sMsg[r * SM + 65] = d1;
    sMsg[r * SM + 66] = d2v;
    for (int c = 67; c < SM; ++c) sMsg[r * SM + c] = (__bf16)0.0f;
  }
  __syncthreads();

  const int l15 = lane & 15, quad = lane >> 4;
  // ---- layer 1: [64 x 96] @ [96 x 128] -> sH; wave wv owns n-tile wv ----
  {
    floatx4 acc[4] = {};
    const __bf16* wrow = W1t + (wv * 16 + l15) * 96;
#pragma unroll
    for (int ks = 0; ks < 3; ++ks) {
      const bf16x8 bfrag = *(const bf16x8*)(wrow + ks * 32 + quad * 8);
#pragma unroll
      for (int mt = 0; mt < 4; ++mt) {
        const bf16x8 afrag = *(const bf16x8*)&sMsg[(mt * 16 + l15) * SM + ks * 32 + quad * 8];
        acc[mt] = __builtin_amdgcn_mfma_f32_16x16x32_bf16(afrag, bfrag, acc[mt], 0, 0, 0);
      }
    }
    const int col = wv * 16 + l15;
    const float bias = b1[col];
#pragma unroll
    for (int mt = 0; mt < 4; ++mt)
#pragma unroll
      for (int rg = 0; rg < 4; ++rg) {
        const int row = mt * 16 + quad * 4 + rg;
        float v = acc[mt][rg] + bias;
        v = v > 0.0f ? v : 0.0f;
        sH[row * SH + col] = (__bf16)v;
      }
  }
  __syncthreads();
  // ---- layer 2: [64 x 128] @ [128 x 128], IN PLACE on sH ----
  {
    floatx4 acc[4] = {};
    const __bf16* wrow = W2t + (wv * 16 + l15) * 128;
#pragma unroll
    for (int ks = 0; ks < 4; ++ks) {
      const bf16x8 bfrag = *(const bf16x8*)(wrow + ks * 32 + quad * 8);
#pragma unroll
      for (int mt = 0; mt < 4; ++mt) {
        const bf16x8 afrag = *(const bf16x8*)&sH[(mt * 16 + l15) * SH + ks * 32 + quad * 8];
        acc[mt] = __builtin_amdgcn_mfma_f32_16x16x32_bf16(afrag, bfrag, acc[mt], 0, 0, 0);
      }
    }
    __syncthreads();   // all reads of sH complete before overwrite
    const int col = wv * 16 + l15;
    const float bias = b2[col];
#pragma unroll
    for (int mt = 0; mt < 4; ++mt)
#pragma unroll
      for (int rg = 0; rg < 4; ++rg) {
        const int row = mt * 16 + quad * 4 + rg;
        float v = acc[mt][rg] + bias;
        v = v > 0.0f ? v : 0.0f;
        sH[row * SH + col] = (__bf16)v;
      }
  }
  __syncthreads();
  // ---- layer 3: [64 x 128] @ [128 x 256]; wave owns 2 n-tiles; fused masked max ----
  {
    floatx4 acc[2][4] = {};
#pragma unroll
    for (int ks = 0; ks < 4; ++ks) {
      bf16x8 afrag[4];
#pragma unroll
      for (int mt = 0; mt < 4; ++mt)
        afrag[mt] = *(const bf16x8*)&sH[(mt * 16 + l15) * SH + ks * 32 + quad * 8];
#pragma unroll
      for (int i = 0; i < 2; ++i) {
        const bf16x8 bfrag = *(const bf16x8*)(W3t + ((wv * 2 + i) * 16 + l15) * 128 + ks * 32 + quad * 8);
#pragma unroll
        for (int mt = 0; mt < 4; ++mt)
          acc[i][mt] = __builtin_amdgcn_mfma_f32_16x16x32_bf16(afrag[mt], bfrag, acc[i][mt], 0, 0, 0);
      }
    }
#pragma unroll
    for (int i = 0; i < 2; ++i) {
      const int col = (wv * 2 + i) * 16 + l15;
      const float bias = b3[col];
      float mx = 0.0f;  // centroid itself always in-radius => cnt>=1; ReLU >= 0
#pragma unroll
      for (int mt = 0; mt < 4; ++mt)
#pragma unroll
        for (int rg = 0; rg < 4; ++rg) {
          const int row = mt * 16 + quad * 4 + rg;
          float v = acc[i][mt][rg] + bias;
          v = v > 0.0f ? v : 0.0f;
          if (row < cnt) mx = fmaxf(mx, v);
        }
      mx = fmaxf(mx, __shfl_xor(mx, 16));
      mx = fmaxf(mx, __shfl_xor(mx, 32));
      if (quad == 0) outX[(long)e * F3 + col] = mx;
    }
  }
}

extern "C" void kernel_launch(void* const* d_in, const int* in_sizes, int n_in,
                              void* d_out, int out_size, void* d_ws, size_t ws_size,
                              hipStream_t stream) {
  const float* x   = (const float*)d_in[0];
  const float* pos = (const float*)d_in[1];
  const float* W1  = (const float*)d_in[4];
  const float* b1  = (const float*)d_in[5];
  const float* W2  = (const float*)d_in[6];
  const float* b2  = (const float*)d_in[7];
  const float* W3  = (const float*)d_in[8];
  const float* b3  = (const float*)d_in[9];

  // Workspace layout (~4.25 MB)
  char* ws = (char*)d_ws;
  int*    fpsIdx = (int*)(ws);                 // 8192*4        = 32768
  float*  ctr    = (float*)(ws + 32768);       // 8192*3*4      = 98304   (ends 131072)
  __bf16* W1t    = (__bf16*)(ws + 131072);     // 128*96*2      = 24576   (ends 155648)
  __bf16* W2t    = (__bf16*)(ws + 155648);     // 128*128*2     = 32768   (ends 188416)
  __bf16* W3t    = (__bf16*)(ws + 188416);     // 256*128*2     = 65536   (ends 253952)
  __bf16* xb     = (__bf16*)(ws + 253952);     // 32768*64*2    = 4194304 (ends 4448256)

  float* outX = (float*)d_out;                 // [8192,256]
  float* outP = outX + (long)EE * F3;          // [8192,3]
  float* outB = outP + (long)EE * 3;           // [8192]
  float* outS = outB + EE;                     // [8192]

  fps_kernel<<<BB, 1024, 0, stream>>>(pos, fpsIdx, ctr);
  xcvt_kernel<<<2048, 256, 0, stream>>>(x, xb);
  wprep_kernel<<<240, 256, 0, stream>>>(W1, W2, W3, W1t, W2t, W3t);
  tail_kernel<<<EE / 256, 256, 0, stream>>>(pos, fpsIdx, outP, outB, outS);
  mlp_kernel<<<EE, 512, 0, stream>>>(xb, pos, ctr, W1t, W2t, W3t, b1, b2, b3, outX);
}

// Round 5
// 1444.646 us; speedup vs baseline: 1.8533x; 1.3615x over previous
//
#include <hip/hip_runtime.h>
#include <stdint.h>

#define BB 8
#define NN 4096
#define CC 64
#define MM 1024
#define EE (BB*MM)   // 8192 centroids
#define KK 64        // max neighbors
#define F3 256       // output channels
#define SM 104       // msg LDS stride (elements), 16B-aligned rows (208 B)
#define SH 136       // h LDS stride (elements), 16B-aligned rows (272 B)
#define CAP 768      // candidate buffer

typedef __bf16 bf16x8 __attribute__((ext_vector_type(8)));
typedef float floatx4 __attribute__((ext_vector_type(4)));

// ---- wave64 reductions via DPP (VALU latency, no LDS) ----
// Positive-f32 bit patterns are order-isomorphic to u32, so u-max on bits == f-max.
#define DPP_MAXSTEP(ctrl, rmask) { \
    unsigned o = (unsigned)__builtin_amdgcn_update_dpp(0, (int)v, ctrl, rmask, 0xf, false); \
    v = v > o ? v : o; }
__device__ __forceinline__ unsigned wave_umax_u32(unsigned v) {
  DPP_MAXSTEP(0x111, 0xf)   // row_shr:1
  DPP_MAXSTEP(0x112, 0xf)   // row_shr:2
  DPP_MAXSTEP(0x114, 0xf)   // row_shr:4
  DPP_MAXSTEP(0x118, 0xf)   // row_shr:8
  DPP_MAXSTEP(0x142, 0xa)   // row_bcast:15 -> rows 1,3
  DPP_MAXSTEP(0x143, 0xc)   // row_bcast:31 -> rows 2,3
  return (unsigned)__builtin_amdgcn_readlane((int)v, 63);
}
#define DPP_MINSTEP(ctrl, rmask) { \
    unsigned o = (unsigned)__builtin_amdgcn_update_dpp((int)0xffffffffu, (int)v, ctrl, rmask, 0xf, false); \
    v = v < o ? v : o; }
__device__ __forceinline__ unsigned wave_umin_u32(unsigned v) {
  DPP_MINSTEP(0x111, 0xf)
  DPP_MINSTEP(0x112, 0xf)
  DPP_MINSTEP(0x114, 0xf)
  DPP_MINSTEP(0x118, 0xf)
  DPP_MINSTEP(0x142, 0xa)
  DPP_MINSTEP(0x143, 0xc)
  return (unsigned)__builtin_amdgcn_readlane((int)v, 63);
}

// ---- FPS (blocks 0..7) + x f32->bf16 (next 1024 blocks) + W transpose (last 120) ----
// FPS: 512 thr, 8 pts/thread, ONE barrier/step, NO global ops inside the loop.
__global__ __launch_bounds__(512) void fps_prep_kernel(
    const float* __restrict__ pos, const float* __restrict__ x,
    const float* __restrict__ W1, const float* __restrict__ W2, const float* __restrict__ W3,
    int* __restrict__ fpsIdx, float* __restrict__ ctr, __bf16* __restrict__ xb,
    __bf16* __restrict__ W1t, __bf16* __restrict__ W2t, __bf16* __restrict__ W3t) {
  __shared__ float4 sP4[NN];                       // 64 KB
  __shared__ unsigned long long sRed[2][8];
  const int blk = blockIdx.x;
  const int t = threadIdx.x;

  if (blk >= BB) {
    int cb = blk - BB;
    if (cb < 1024) {                               // xcvt: 524288 float4s
      const int t4 = cb * 512 + t;
      const float4 v = ((const float4*)x)[t4];
      __bf16 o[4] = {(__bf16)v.x, (__bf16)v.y, (__bf16)v.z, (__bf16)v.w};
      *(uint2*)(xb + (long)t4 * 4) = *(uint2*)o;
    } else {                                       // wprep: 61440 elements
      const int i0 = (cb - 1024) * 512 + t;
      if (i0 < 128 * 96) {
        const int n = i0 / 96, k = i0 % 96;
        W1t[i0] = (k < 67) ? (__bf16)W1[k * 128 + n] : (__bf16)0.0f;
      } else if (i0 < 128 * 96 + 128 * 128) {
        const int i = i0 - 128 * 96;
        const int n = i / 128, k = i % 128;
        W2t[i] = (__bf16)W2[k * 128 + n];
      } else {
        const int i = i0 - (128 * 96 + 128 * 128);
        const int n = i / 128, k = i % 128;
        W3t[i] = (__bf16)W3[k * 256 + n];
      }
    }
    return;
  }

  const int g = blk;
  const int lane = t & 63, wv = t >> 6;
  float px[8], py[8], pz[8], mind[8];
#pragma unroll
  for (int j = 0; j < 8; ++j) {
    const int p = t + (j << 9);
    const long base = ((long)g * NN + p) * 3;
    px[j] = pos[base + 0];
    py[j] = pos[base + 1];
    pz[j] = pos[base + 2];
    mind[j] = 1e10f;
    sP4[p] = make_float4(px[j], py[j], pz[j], 0.0f);
  }
  __syncthreads();
  float wx = sP4[0].x, wy = sP4[0].y, wz = sP4[0].z;
  int win0 = 0, win1 = 0;
  for (int s = 1; s < MM; ++s) {
    unsigned bb = 0u, bidx = (unsigned)t;
#pragma unroll
    for (int j = 0; j < 8; ++j) {
      const float dx = __fsub_rn(px[j], wx);
      const float dy = __fsub_rn(py[j], wy);
      const float dz = __fsub_rn(pz[j], wz);
      const float d2 = __fadd_rn(__fadd_rn(__fmul_rn(dx, dx), __fmul_rn(dy, dy)), __fmul_rn(dz, dz));
      mind[j] = fminf(mind[j], d2);
      const unsigned mb = __float_as_uint(mind[j]);
      if (mb > bb) { bb = mb; bidx = (unsigned)(t + (j << 9)); }  // strict > : keep smaller idx on tie
    }
    const unsigned maxv = wave_umax_u32(bb);
    const unsigned cand = (bb == maxv) ? bidx : 0xffffffffu;
    const unsigned minidx = wave_umin_u32(cand);
    if (lane == 0)
      sRed[s & 1][wv] = ((unsigned long long)maxv << 32) | (unsigned long long)(~minidx);
    __syncthreads();
    unsigned long long m = sRed[s & 1][0];
#pragma unroll
    for (int w = 1; w < 8; ++w) {
      const unsigned long long o = sRed[s & 1][w];
      m = o > m ? o : m;
    }
    const int widx = (int)(~(unsigned)m);
    const float4 wp = sP4[widx];
    wx = wp.x; wy = wp.y; wz = wp.z;
    if (s == t)       win0 = widx;
    if (s == t + 512) win1 = widx;
  }
  // Epilogue: batched global writes (thread t owns steps t and t+512).
  {
    const long e0 = (long)g * MM + t;
    const float4 p0 = sP4[win0];
    fpsIdx[e0] = win0;
    ctr[e0 * 3 + 0] = p0.x; ctr[e0 * 3 + 1] = p0.y; ctr[e0 * 3 + 2] = p0.z;
    const long e1 = e0 + 512;
    const float4 p1 = sP4[win1];
    fpsIdx[e1] = win1;
    ctr[e1 * 3 + 0] = p1.x; ctr[e1 * 3 + 1] = p1.y; ctr[e1 * 3 + 2] = p1.z;
  }
}

// ---- Fused radius-search + top-K + gather + 3-layer MLP (bf16 MFMA) + masked max ----
// One block (512 thr = 8 waves) per centroid; tail outputs folded in.
__global__ __launch_bounds__(512) void mlp_kernel(const __bf16* __restrict__ xb,
    const float* __restrict__ pos, const float* __restrict__ ctr,
    const int* __restrict__ fpsIdx,
    const __bf16* __restrict__ W1t, const __bf16* __restrict__ W2t,
    const __bf16* __restrict__ W3t,
    const float* __restrict__ b1, const float* __restrict__ b2,
    const float* __restrict__ b3,
    float* __restrict__ outX, float* __restrict__ outP,
    float* __restrict__ outB, float* __restrict__ outS) {
  __shared__ __align__(16) __bf16 sMsg[64 * SM];   // 13312 B; overlays sD+sI (6144 B)
  __shared__ __align__(16) __bf16 sH[64 * SH];     // 17408 B
  __shared__ int sSel[KK];
  __shared__ int sCnt;
  float* sD = (float*)sMsg;          // [CAP]
  int*   sI = ((int*)sMsg) + CAP;    // [CAP]

  const int e = blockIdx.x;
  const int t = threadIdx.x;
  const int b = e >> 10;
  const int lane = t & 63, wv = t >> 6;

  if (t == 0) sCnt = 0;
  const float cx = ctr[(long)e * 3 + 0];
  const float cy = ctr[(long)e * 3 + 1];
  const float cz = ctr[(long)e * 3 + 2];
  // tail outputs (exact copies / integer casts)
  if (t < 3) outP[(long)e * 3 + t] = ctr[(long)e * 3 + t];
  if (t == 3) { outB[e] = (float)b; outS[e] = (float)(b * NN + fpsIdx[e]); }
  const float R2 = (float)(0.2 * 0.2);
  const long pbase = (long)b * NN * 3;
  __syncthreads();

  // Phase A: scan 4096 points; compact in-radius candidates to LDS (order-free).
#pragma unroll
  for (int q = 0; q < NN / 512; ++q) {
    const int p = t + q * 512;
    const float dx = __fsub_rn(cx, pos[pbase + (long)p * 3 + 0]);
    const float dy = __fsub_rn(cy, pos[pbase + (long)p * 3 + 1]);
    const float dz = __fsub_rn(cz, pos[pbase + (long)p * 3 + 2]);
    const float d2 = __fadd_rn(__fadd_rn(__fmul_rn(dx, dx), __fmul_rn(dy, dy)), __fmul_rn(dz, dz));
    if (d2 < R2) {
      const int slot = atomicAdd(&sCnt, 1);
      if (slot < CAP) { sD[slot] = d2; sI[slot] = p; }
    }
  }
  __syncthreads();
  int cnt = sCnt; cnt = cnt > CAP ? CAP : cnt;

  // Phase B: if over K, select the K smallest by (d2, idx); else take all.
  if (cnt > KK) {
    if (wv == 0) {
      float ld[CAP / 64]; int li[CAP / 64];
#pragma unroll
      for (int q = 0; q < CAP / 64; ++q) {
        const int pp = lane + q * 64;
        if (pp < cnt) { ld[q] = sD[pp]; li[q] = sI[pp]; }
        else          { ld[q] = 3.0e38f; li[q] = 0x7fffffff; }
      }
      for (int round = 0; round < KK; ++round) {
        float bv = ld[0]; int bi = li[0];
#pragma unroll
        for (int q = 1; q < CAP / 64; ++q)
          if (ld[q] < bv || (ld[q] == bv && li[q] < bi)) { bv = ld[q]; bi = li[q]; }
#pragma unroll
        for (int off = 32; off >= 1; off >>= 1) {
          const float ov = __shfl_xor(bv, off);
          const int   oi = __shfl_xor(bi, off);
          if (ov < bv || (ov == bv && oi < bi)) { bv = ov; bi = oi; }
        }
        if (lane == 0) sSel[round] = bi;
#pragma unroll
        for (int q = 0; q < CAP / 64; ++q)
          if (li[q] == bi) ld[q] = 3.0e38f;
      }
    }
    cnt = KK;
  } else {
    if (wv == 0 && lane < cnt) sSel[lane] = sI[lane];
  }
  __syncthreads();   // sD/sI dead from here; sMsg may be written

  // Phase C: stage msg tile [64 x (64 feat | 3 dpos | zero-pad)] into LDS as bf16.
  {
    const int r = t >> 3, p = t & 7;
    uint4 val = make_uint4(0u, 0u, 0u, 0u);
    int j = 0;
    if (r < cnt) j = b * NN + sSel[r];
    if (r < cnt) val = *(const uint4*)(xb + (long)j * CC + p * 8);
    __syncthreads();  // ensure all Phase-B reads of sD/sI done before overwrite
    *(uint4*)&sMsg[r * SM + p * 8] = val;
  }
  if (t < 64) {
    const int r = t;
    __bf16 d0 = (__bf16)0.0f, d1 = (__bf16)0.0f, d2v = (__bf16)0.0f;
    if (r < cnt) {
      const long j = pbase + (long)sSel[r] * 3;
      d0  = (__bf16)__fsub_rn(pos[j + 0], cx);
      d1  = (__bf16)__fsub_rn(pos[j + 1], cy);
      d2v = (__bf16)__fsub_rn(pos[j + 2], cz);
    }
    sMsg[r * SM + 64] = d0;
    sMsg[r * SM + 65] = d1;
    sMsg[r * SM + 66] = d2v;
    for (int c = 67; c < SM; ++c) sMsg[r * SM + c] = (__bf16)0.0f;
  }
  __syncthreads();

  const int l15 = lane & 15, quad = lane >> 4;
  // ---- layer 1: [64 x 96] @ [96 x 128] -> sH; wave wv owns n-tile wv ----
  {
    floatx4 acc[4] = {};
    const __bf16* wrow = W1t + (wv * 16 + l15) * 96;
#pragma unroll
    for (int ks = 0; ks < 3; ++ks) {
      const bf16x8 bfrag = *(const bf16x8*)(wrow + ks * 32 + quad * 8);
#pragma unroll
      for (int mt = 0; mt < 4; ++mt) {
        const bf16x8 afrag = *(const bf16x8*)&sMsg[(mt * 16 + l15) * SM + ks * 32 + quad * 8];
        acc[mt] = __builtin_amdgcn_mfma_f32_16x16x32_bf16(afrag, bfrag, acc[mt], 0, 0, 0);
      }
    }
    const int col = wv * 16 + l15;
    const float bias = b1[col];
#pragma unroll
    for (int mt = 0; mt < 4; ++mt)
#pragma unroll
      for (int rg = 0; rg < 4; ++rg) {
        const int row = mt * 16 + quad * 4 + rg;
        float v = acc[mt][rg] + bias;
        v = v > 0.0f ? v : 0.0f;
        sH[row * SH + col] = (__bf16)v;
      }
  }
  __syncthreads();
  // ---- layer 2: [64 x 128] @ [128 x 128], IN PLACE on sH ----
  {
    floatx4 acc[4] = {};
    const __bf16* wrow = W2t + (wv * 16 + l15) * 128;
#pragma unroll
    for (int ks = 0; ks < 4; ++ks) {
      const bf16x8 bfrag = *(const bf16x8*)(wrow + ks * 32 + quad * 8);
#pragma unroll
      for (int mt = 0; mt < 4; ++mt) {
        const bf16x8 afrag = *(const bf16x8*)&sH[(mt * 16 + l15) * SH + ks * 32 + quad * 8];
        acc[mt] = __builtin_amdgcn_mfma_f32_16x16x32_bf16(afrag, bfrag, acc[mt], 0, 0, 0);
      }
    }
    __syncthreads();   // all reads of sH complete before overwrite
    const int col = wv * 16 + l15;
    const float bias = b2[col];
#pragma unroll
    for (int mt = 0; mt < 4; ++mt)
#pragma unroll
      for (int rg = 0; rg < 4; ++rg) {
        const int row = mt * 16 + quad * 4 + rg;
        float v = acc[mt][rg] + bias;
        v = v > 0.0f ? v : 0.0f;
        sH[row * SH + col] = (__bf16)v;
      }
  }
  __syncthreads();
  // ---- layer 3: [64 x 128] @ [128 x 256]; wave owns 2 n-tiles; fused masked max ----
  {
    floatx4 acc[2][4] = {};
#pragma unroll
    for (int ks = 0; ks < 4; ++ks) {
      bf16x8 afrag[4];
#pragma unroll
      for (int mt = 0; mt < 4; ++mt)
        afrag[mt] = *(const bf16x8*)&sH[(mt * 16 + l15) * SH + ks * 32 + quad * 8];
#pragma unroll
      for (int i = 0; i < 2; ++i) {
        const bf16x8 bfrag = *(const bf16x8*)(W3t + ((wv * 2 + i) * 16 + l15) * 128 + ks * 32 + quad * 8);
#pragma unroll
        for (int mt = 0; mt < 4; ++mt)
          acc[i][mt] = __builtin_amdgcn_mfma_f32_16x16x32_bf16(afrag[mt], bfrag, acc[i][mt], 0, 0, 0);
      }
    }
#pragma unroll
    for (int i = 0; i < 2; ++i) {
      const int col = (wv * 2 + i) * 16 + l15;
      const float bias = b3[col];
      float mx = 0.0f;  // centroid itself always in-radius => cnt>=1; ReLU >= 0
#pragma unroll
      for (int mt = 0; mt < 4; ++mt)
#pragma unroll
        for (int rg = 0; rg < 4; ++rg) {
          const int row = mt * 16 + quad * 4 + rg;
          float v = acc[i][mt][rg] + bias;
          v = v > 0.0f ? v : 0.0f;
          if (row < cnt) mx = fmaxf(mx, v);
        }
      mx = fmaxf(mx, __shfl_xor(mx, 16));
      mx = fmaxf(mx, __shfl_xor(mx, 32));
      if (quad == 0) outX[(long)e * F3 + col] = mx;
    }
  }
}

extern "C" void kernel_launch(void* const* d_in, const int* in_sizes, int n_in,
                              void* d_out, int out_size, void* d_ws, size_t ws_size,
                              hipStream_t stream) {
  const float* x   = (const float*)d_in[0];
  const float* pos = (const float*)d_in[1];
  const float* W1  = (const float*)d_in[4];
  const float* b1  = (const float*)d_in[5];
  const float* W2  = (const float*)d_in[6];
  const float* b2  = (const float*)d_in[7];
  const float* W3  = (const float*)d_in[8];
  const float* b3  = (const float*)d_in[9];

  // Workspace layout (~4.25 MB)
  char* ws = (char*)d_ws;
  int*    fpsIdx = (int*)(ws);                 // 8192*4        = 32768
  float*  ctr    = (float*)(ws + 32768);       // 8192*3*4      = 98304   (ends 131072)
  __bf16* W1t    = (__bf16*)(ws + 131072);     // 128*96*2      = 24576   (ends 155648)
  __bf16* W2t    = (__bf16*)(ws + 155648);     // 128*128*2     = 32768   (ends 188416)
  __bf16* W3t    = (__bf16*)(ws + 188416);     // 256*128*2     = 65536   (ends 253952)
  __bf16* xb     = (__bf16*)(ws + 253952);     // 32768*64*2    = 4194304 (ends 4448256)

  float* outX = (float*)d_out;                 // [8192,256]
  float* outP = outX + (long)EE * F3;          // [8192,3]
  float* outB = outP + (long)EE * 3;           // [8192]
  float* outS = outB + EE;                     // [8192]

  // blocks: 8 FPS + 1024 xcvt + 120 wprep
  fps_prep_kernel<<<8 + 1024 + 120, 512, 0, stream>>>(pos, x, W1, W2, W3,
                                                      fpsIdx, ctr, xb, W1t, W2t, W3t);
  mlp_kernel<<<EE, 512, 0, stream>>>(xb, pos, ctr, fpsIdx, W1t, W2t, W3t,
                                     b1, b2, b3, outX, outP, outB, outS);
}

// Round 6
// 859.611 us; speedup vs baseline: 3.1146x; 1.6806x over previous
//
#include <hip/hip_runtime.h>
#include <stdint.h>

#define BB 8
#define NN 4096
#define CC 64
#define MM 1024
#define EE (BB*MM)   // 8192 centroids
#define KK 64        // max neighbors
#define F3 256       // output channels
#define SM 104       // msg LDS stride (elements), 16B-aligned rows (208 B)
#define SH 136       // h LDS stride (elements), 16B-aligned rows (272 B)
#define CAP 768      // candidate buffer

typedef __bf16 bf16x8 __attribute__((ext_vector_type(8)));
typedef float floatx4 __attribute__((ext_vector_type(4)));

// ---- wave64 reductions via DPP (VALU latency, no LDS) ----
#define DPP_MAXSTEP(ctrl, rmask) { \
    unsigned o = (unsigned)__builtin_amdgcn_update_dpp(0, (int)v, ctrl, rmask, 0xf, false); \
    v = v > o ? v : o; }
__device__ __forceinline__ unsigned wave_umax_u32(unsigned v) {
  DPP_MAXSTEP(0x111, 0xf)
  DPP_MAXSTEP(0x112, 0xf)
  DPP_MAXSTEP(0x114, 0xf)
  DPP_MAXSTEP(0x118, 0xf)
  DPP_MAXSTEP(0x142, 0xa)
  DPP_MAXSTEP(0x143, 0xc)
  return (unsigned)__builtin_amdgcn_readlane((int)v, 63);
}
#define DPP_MINSTEP(ctrl, rmask) { \
    unsigned o = (unsigned)__builtin_amdgcn_update_dpp((int)0xffffffffu, (int)v, ctrl, rmask, 0xf, false); \
    v = v < o ? v : o; }
__device__ __forceinline__ unsigned wave_umin_u32(unsigned v) {
  DPP_MINSTEP(0x111, 0xf)
  DPP_MINSTEP(0x112, 0xf)
  DPP_MINSTEP(0x114, 0xf)
  DPP_MINSTEP(0x118, 0xf)
  DPP_MINSTEP(0x142, 0xa)
  DPP_MINSTEP(0x143, 0xc)
  return (unsigned)__builtin_amdgcn_readlane((int)v, 63);
}

// ---- FPS (blocks 0..7) + W transpose (8..127) + pos->float4 (128..191) ----
__global__ __launch_bounds__(512) void fps_prep_kernel(
    const float* __restrict__ pos,
    const float* __restrict__ W1, const float* __restrict__ W2, const float* __restrict__ W3,
    int* __restrict__ fpsIdx, float* __restrict__ ctr,
    __bf16* __restrict__ W1t, __bf16* __restrict__ W2t, __bf16* __restrict__ W3t,
    float4* __restrict__ pos4) {
  __shared__ float4 sP4[NN];                       // 64 KB
  __shared__ unsigned long long sRed[2][8];
  const int blk = blockIdx.x;
  const int t = threadIdx.x;

  if (blk >= BB) {
    if (blk < 128) {                               // wprep: 61440 elements
      const int i0 = (blk - 8) * 512 + t;
      if (i0 < 128 * 96) {
        const int n = i0 / 96, k = i0 % 96;
        W1t[i0] = (k < 67) ? (__bf16)W1[k * 128 + n] : (__bf16)0.0f;
      } else if (i0 < 128 * 96 + 128 * 128) {
        const int i = i0 - 128 * 96;
        const int n = i / 128, k = i % 128;
        W2t[i] = (__bf16)W2[k * 128 + n];
      } else {
        const int i = i0 - (128 * 96 + 128 * 128);
        const int n = i / 128, k = i % 128;
        W3t[i] = (__bf16)W3[k * 256 + n];
      }
    } else {                                       // posp: 32768 points
      const int i = (blk - 128) * 512 + t;
      pos4[i] = make_float4(pos[(long)i * 3 + 0], pos[(long)i * 3 + 1],
                            pos[(long)i * 3 + 2], 0.0f);
    }
    return;
  }

  const int g = blk;
  const int lane = t & 63, wv = t >> 6;
  float px[8], py[8], pz[8], mind[8];
#pragma unroll
  for (int j = 0; j < 8; ++j) {
    const int p = t + (j << 9);
    const long base = ((long)g * NN + p) * 3;
    px[j] = pos[base + 0];
    py[j] = pos[base + 1];
    pz[j] = pos[base + 2];
    mind[j] = 1e10f;
    sP4[p] = make_float4(px[j], py[j], pz[j], 0.0f);
  }
  __syncthreads();
  float wx = sP4[0].x, wy = sP4[0].y, wz = sP4[0].z;
  int win0 = 0, win1 = 0;
  for (int s = 1; s < MM; ++s) {
    unsigned bb = 0u, bidx = (unsigned)t;
#pragma unroll
    for (int j = 0; j < 8; ++j) {
      const float dx = __fsub_rn(px[j], wx);
      const float dy = __fsub_rn(py[j], wy);
      const float dz = __fsub_rn(pz[j], wz);
      const float d2 = __fadd_rn(__fadd_rn(__fmul_rn(dx, dx), __fmul_rn(dy, dy)), __fmul_rn(dz, dz));
      mind[j] = fminf(mind[j], d2);
      const unsigned mb = __float_as_uint(mind[j]);
      if (mb > bb) { bb = mb; bidx = (unsigned)(t + (j << 9)); }
    }
    const unsigned maxv = wave_umax_u32(bb);
    const unsigned cand = (bb == maxv) ? bidx : 0xffffffffu;
    const unsigned minidx = wave_umin_u32(cand);
    if (lane == 0)
      sRed[s & 1][wv] = ((unsigned long long)maxv << 32) | (unsigned long long)(~minidx);
    __syncthreads();
    unsigned long long m = sRed[s & 1][0];
#pragma unroll
    for (int w = 1; w < 8; ++w) {
      const unsigned long long o = sRed[s & 1][w];
      m = o > m ? o : m;
    }
    const int widx = (int)(~(unsigned)m);
    const float4 wp = sP4[widx];
    wx = wp.x; wy = wp.y; wz = wp.z;
    if (s == t)       win0 = widx;
    if (s == t + 512) win1 = widx;
  }
  {
    const long e0 = (long)g * MM + t;
    const float4 p0 = sP4[win0];
    fpsIdx[e0] = win0;
    ctr[e0 * 3 + 0] = p0.x; ctr[e0 * 3 + 1] = p0.y; ctr[e0 * 3 + 2] = p0.z;
    const long e1 = e0 + 512;
    const float4 p1 = sP4[win1];
    fpsIdx[e1] = win1;
    ctr[e1 * 3 + 0] = p1.x; ctr[e1 * 3 + 1] = p1.y; ctr[e1 * 3 + 2] = p1.z;
  }
}

// ---- Fused radius-search + rank-top-K + gather + 3-layer MLP (MFMA) + masked max ----
// One block (512 thr = 8 waves) per centroid; tail outputs folded in.
__global__ __launch_bounds__(512) void mlp_kernel(const float* __restrict__ x,
    const float4* __restrict__ pos4, const float* __restrict__ ctr,
    const int* __restrict__ fpsIdx,
    const __bf16* __restrict__ W1t, const __bf16* __restrict__ W2t,
    const __bf16* __restrict__ W3t,
    const float* __restrict__ b1, const float* __restrict__ b2,
    const float* __restrict__ b3,
    float* __restrict__ outX, float* __restrict__ outP,
    float* __restrict__ outB, float* __restrict__ outS) {
  __shared__ __align__(16) __bf16 sMsg[64 * SM];   // 13312 B; overlays sDI (6144 B)
  __shared__ __align__(16) __bf16 sH[64 * SH];     // 17408 B
  __shared__ int sSel[KK];
  __shared__ int sCnt;
  unsigned long long* sDI = (unsigned long long*)sMsg;  // [CAP] packed (d2bits<<32 | idx)

  const int e = blockIdx.x;
  const int t = threadIdx.x;
  const int b = e >> 10;
  const int lane = t & 63, wv = t >> 6;

  if (t == 0) sCnt = 0;
  const float cx = ctr[(long)e * 3 + 0];
  const float cy = ctr[(long)e * 3 + 1];
  const float cz = ctr[(long)e * 3 + 2];
  if (t < 3) outP[(long)e * 3 + t] = ctr[(long)e * 3 + t];
  if (t == 3) { outB[e] = (float)b; outS[e] = (float)(b * NN + fpsIdx[e]); }
  const float R2 = (float)(0.2 * 0.2);
  __syncthreads();

  // Phase A: scan 4096 points (float4 loads); ballot-compact candidates to LDS.
#pragma unroll
  for (int q = 0; q < NN / 512; ++q) {
    const int p = t + q * 512;
    const float4 P = pos4[b * NN + p];
    const float dx = __fsub_rn(cx, P.x);
    const float dy = __fsub_rn(cy, P.y);
    const float dz = __fsub_rn(cz, P.z);
    const float d2 = __fadd_rn(__fadd_rn(__fmul_rn(dx, dx), __fmul_rn(dy, dy)), __fmul_rn(dz, dz));
    const bool v = d2 < R2;
    const unsigned long long mask = __ballot(v);
    int wbase = 0;
    if (lane == 0 && mask) wbase = atomicAdd(&sCnt, (int)__popcll(mask));
    wbase = __shfl(wbase, 0);
    if (v) {
      const int off = wbase + (int)__popcll(mask & ((1ull << lane) - 1ull));
      if (off < CAP)
        sDI[off] = ((unsigned long long)__float_as_uint(d2) << 32) | (unsigned)p;
    }
  }
  __syncthreads();
  int cnt = sCnt; cnt = cnt > CAP ? CAP : cnt;
  const int nsel = cnt < KK ? cnt : KK;

  // Phase B: parallel rank selection. rank(i) = #{j : key_j < key_i}; keep rank<K.
  for (int i = t; i < cnt; i += 512) {
    const unsigned long long my = sDI[i];
    int rank = 0;
#pragma unroll 8
    for (int j = 0; j < cnt; ++j) rank += (sDI[j] < my) ? 1 : 0;
    if (rank < KK) sSel[rank] = (int)(unsigned)(my & 0xffffffffu);
  }
  __syncthreads();   // sDI dead from here; sMsg may be written
  cnt = nsel;

  // Phase C: stage msg tile [64 x (64 feat | 3 dpos | zero-pad)] into LDS as bf16.
  {
    const int r = t >> 3, p = t & 7;
    float4 a = make_float4(0.f, 0.f, 0.f, 0.f), c4 = a;
    if (r < cnt) {
      const float* xr = x + (long)(b * NN + sSel[r]) * CC + p * 8;
      a  = *(const float4*)xr;
      c4 = *(const float4*)(xr + 4);
    }
    __bf16 o[8] = {(__bf16)a.x, (__bf16)a.y, (__bf16)a.z, (__bf16)a.w,
                   (__bf16)c4.x, (__bf16)c4.y, (__bf16)c4.z, (__bf16)c4.w};
    *(uint4*)&sMsg[r * SM + p * 8] = *(uint4*)o;
  }
  if (t < 64) {
    const int r = t;
    __bf16 d0 = (__bf16)0.0f, d1 = (__bf16)0.0f, d2v = (__bf16)0.0f;
    if (r < cnt) {
      const float4 P = pos4[b * NN + sSel[r]];
      d0  = (__bf16)__fsub_rn(P.x, cx);
      d1  = (__bf16)__fsub_rn(P.y, cy);
      d2v = (__bf16)__fsub_rn(P.z, cz);
    }
    sMsg[r * SM + 64] = d0;
    sMsg[r * SM + 65] = d1;
    sMsg[r * SM + 66] = d2v;
    for (int c = 67; c < SM; ++c) sMsg[r * SM + c] = (__bf16)0.0f;
  }
  __syncthreads();

  const int l15 = lane & 15, quad = lane >> 4;
  // ---- layer 1: [64 x 96] @ [96 x 128] -> sH; wave wv owns n-tile wv ----
  {
    floatx4 acc[4] = {};
    const __bf16* wrow = W1t + (wv * 16 + l15) * 96;
#pragma unroll
    for (int ks = 0; ks < 3; ++ks) {
      const bf16x8 bfrag = *(const bf16x8*)(wrow + ks * 32 + quad * 8);
#pragma unroll
      for (int mt = 0; mt < 4; ++mt) {
        const bf16x8 afrag = *(const bf16x8*)&sMsg[(mt * 16 + l15) * SM + ks * 32 + quad * 8];
        acc[mt] = __builtin_amdgcn_mfma_f32_16x16x32_bf16(afrag, bfrag, acc[mt], 0, 0, 0);
      }
    }
    const int col = wv * 16 + l15;
    const float bias = b1[col];
#pragma unroll
    for (int mt = 0; mt < 4; ++mt)
#pragma unroll
      for (int rg = 0; rg < 4; ++rg) {
        const int row = mt * 16 + quad * 4 + rg;
        float v = acc[mt][rg] + bias;
        v = v > 0.0f ? v : 0.0f;
        sH[row * SH + col] = (__bf16)v;
      }
  }
  __syncthreads();
  // ---- layer 2: [64 x 128] @ [128 x 128], IN PLACE on sH ----
  {
    floatx4 acc[4] = {};
    const __bf16* wrow = W2t + (wv * 16 + l15) * 128;
#pragma unroll
    for (int ks = 0; ks < 4; ++ks) {
      const bf16x8 bfrag = *(const bf16x8*)(wrow + ks * 32 + quad * 8);
#pragma unroll
      for (int mt = 0; mt < 4; ++mt) {
        const bf16x8 afrag = *(const bf16x8*)&sH[(mt * 16 + l15) * SH + ks * 32 + quad * 8];
        acc[mt] = __builtin_amdgcn_mfma_f32_16x16x32_bf16(afrag, bfrag, acc[mt], 0, 0, 0);
      }
    }
    __syncthreads();
    const int col = wv * 16 + l15;
    const float bias = b2[col];
#pragma unroll
    for (int mt = 0; mt < 4; ++mt)
#pragma unroll
      for (int rg = 0; rg < 4; ++rg) {
        const int row = mt * 16 + quad * 4 + rg;
        float v = acc[mt][rg] + bias;
        v = v > 0.0f ? v : 0.0f;
        sH[row * SH + col] = (__bf16)v;
      }
  }
  __syncthreads();
  // ---- layer 3: [64 x 128] @ [128 x 256]; wave owns 2 n-tiles; fused masked max ----
  {
    floatx4 acc[2][4] = {};
#pragma unroll
    for (int ks = 0; ks < 4; ++ks) {
      bf16x8 afrag[4];
#pragma unroll
      for (int mt = 0; mt < 4; ++mt)
        afrag[mt] = *(const bf16x8*)&sH[(mt * 16 + l15) * SH + ks * 32 + quad * 8];
#pragma unroll
      for (int i = 0; i < 2; ++i) {
        const bf16x8 bfrag = *(const bf16x8*)(W3t + ((wv * 2 + i) * 16 + l15) * 128 + ks * 32 + quad * 8);
#pragma unroll
        for (int mt = 0; mt < 4; ++mt)
          acc[i][mt] = __builtin_amdgcn_mfma_f32_16x16x32_bf16(afrag[mt], bfrag, acc[i][mt], 0, 0, 0);
      }
    }
#pragma unroll
    for (int i = 0; i < 2; ++i) {
      const int col = (wv * 2 + i) * 16 + l15;
      const float bias = b3[col];
      float mx = 0.0f;  // centroid itself always in-radius => cnt>=1; ReLU >= 0
#pragma unroll
      for (int mt = 0; mt < 4; ++mt)
#pragma unroll
        for (int rg = 0; rg < 4; ++rg) {
          const int row = mt * 16 + quad * 4 + rg;
          float v = acc[i][mt][rg] + bias;
          v = v > 0.0f ? v : 0.0f;
          if (row < cnt) mx = fmaxf(mx, v);
        }
      mx = fmaxf(mx, __shfl_xor(mx, 16));
      mx = fmaxf(mx, __shfl_xor(mx, 32));
      if (quad == 0) outX[(long)e * F3 + col] = mx;
    }
  }
}

extern "C" void kernel_launch(void* const* d_in, const int* in_sizes, int n_in,
                              void* d_out, int out_size, void* d_ws, size_t ws_size,
                              hipStream_t stream) {
  const float* x   = (const float*)d_in[0];
  const float* pos = (const float*)d_in[1];
  const float* W1  = (const float*)d_in[4];
  const float* b1  = (const float*)d_in[5];
  const float* W2  = (const float*)d_in[6];
  const float* b2  = (const float*)d_in[7];
  const float* W3  = (const float*)d_in[8];
  const float* b3  = (const float*)d_in[9];

  // Workspace layout (~778 KB)
  char* ws = (char*)d_ws;
  int*    fpsIdx = (int*)(ws);                 // 8192*4        = 32768
  float*  ctr    = (float*)(ws + 32768);       // 8192*3*4      = 98304   (ends 131072)
  __bf16* W1t    = (__bf16*)(ws + 131072);     // 128*96*2      = 24576   (ends 155648)
  __bf16* W2t    = (__bf16*)(ws + 155648);     // 128*128*2     = 32768   (ends 188416)
  __bf16* W3t    = (__bf16*)(ws + 188416);     // 256*128*2     = 65536   (ends 253952)
  float4* pos4   = (float4*)(ws + 253952);     // 32768*16      = 524288  (ends 778240)

  float* outX = (float*)d_out;                 // [8192,256]
  float* outP = outX + (long)EE * F3;          // [8192,3]
  float* outB = outP + (long)EE * 3;           // [8192]
  float* outS = outB + EE;                     // [8192]

  // blocks: 8 FPS + 120 wprep + 64 posp
  fps_prep_kernel<<<192, 512, 0, stream>>>(pos, W1, W2, W3,
                                           fpsIdx, ctr, W1t, W2t, W3t, pos4);
  mlp_kernel<<<EE, 512, 0, stream>>>(x, pos4, ctr, fpsIdx, W1t, W2t, W3t,
                                     b1, b2, b3, outX, outP, outB, outS);
}